// Round 10
// baseline (186.649 us; speedup 1.0000x reference)
//
#include <hip/hip_runtime.h>
#include <hip/hip_bf16.h>
#include <hip/hip_fp8.h>

// TextualContrastiveLoss: B=4096, D=1024, NUM_CLASSES=100, T=0.5
//   z = l2norm(emb); reps = [z_i; z_j] (8192x1024)
//   sim = reps @ reps^T; e = exp(sim/T) with diag excluded
//   loss = mean_n( log(sum_m e) - log(sum_{m: lab match} e) )
//
// R3: 128x128 fused GEMM + upper-tri symmetry: 171us. R6 dbuf: 158.
// R7: fp8 BKB=128: 136. R8: wave-private barrier-free: regressed (TLP).
// R9: BKB=64, 32KB LDS, 4 blocks/CU: 103us. MfmaUtil 27, VALU 26,
//     conflicts +4cyc/b128 (blk=quad^(r&3) -> only 4 distinct bank
//     starts), pipes sum instead of overlap -> still short on TLP.
// R10: (a) swz(r)=(r^(r>>2))&3 -> 8 bank-starts x 2 lanes = 2-way (free);
//      (b) __launch_bounds__(256,5): 5x32KB = 160KiB exactly, 5 blocks/CU;
//      (c) packed-butterfly epilogue: row sums reduced 16-at-a-time in 15
//          shuffles (lane l15 ends owning row k=l15), cols in 3 -> 36
//          cross-lane ops/wave vs 144, atomics full-width.

#define BHALF 4096
#define N2 8192
#define DK 1024               // elements per row; fp8 => 1024 B
#define TILE 128
#define BKB 64                // K bytes staged per kt (16 kt total)
#define NTILE 64              // 8192/128
#define NBLK 2080             // 64*65/2 upper-tri tiles

typedef __attribute__((ext_vector_type(4))) float f32x4;
typedef __attribute__((ext_vector_type(2))) long v2l;
typedef unsigned char u8;

// exp(s/0.5) = exp2(s * 2*log2(e))
#define EXP_SCALE 2.8853900817779268f

__global__ __launch_bounds__(256) void normalize_kernel(
    const float* __restrict__ emb_i, const float* __restrict__ emb_j,
    u8* __restrict__ reps, float* __restrict__ nomden,
    float* __restrict__ out) {
    int r = blockIdx.x;           // 0..8191
    int t = threadIdx.x;          // 0..255, one float4 each
    int idx = r * 256 + t;
    if (idx < 2 * N2) nomden[idx] = 0.0f;     // fused zero of nom+den
    if (idx == 0) out[0] = 0.0f;
    const float* src = (r < BHALF) ? (emb_i + (size_t)r * DK)
                                   : (emb_j + (size_t)(r - BHALF) * DK);
    float4 v = ((const float4*)src)[t];
    float s = v.x * v.x + v.y * v.y + v.z * v.z + v.w * v.w;
#pragma unroll
    for (int m = 1; m <= 32; m <<= 1) s += __shfl_xor(s, m, 64);
    __shared__ float red[4];
    if ((t & 63) == 0) red[t >> 6] = s;
    __syncthreads();
    float tot = red[0] + red[1] + red[2] + red[3];
    float scale = 1.0f / fmaxf(sqrtf(tot), 1e-12f);
    __hip_fp8_e4m3 q0(v.x * scale), q1(v.y * scale),
                   q2(v.z * scale), q3(v.w * scale);
    uchar4 o = make_uchar4(q0.__x, q1.__x, q2.__x, q3.__x);
    ((uchar4*)(reps + (size_t)r * DK))[t] = o;
}

__global__ __launch_bounds__(256, 5) void gemm_loss_kernel(
    const u8* __restrict__ reps, const int* __restrict__ labels,
    float* __restrict__ nom, float* __restrict__ den) {
    // Double-buffered fp8 tiles: 2 x (A 8KB + B 8KB) = 32 KB.
    // Rows are 64 B = 4 x 16B blocks. Swizzle: LDS slot (row, b) holds
    // global block b ^ swz(row), swz(r) = (r ^ (r>>2)) & 3.
    __shared__ __align__(16) u8 A_s[2][TILE * BKB];
    __shared__ __align__(16) u8 B_s[2][TILE * BKB];

    // upper-triangle decode: row-major over bi<=bj
    int rem = blockIdx.x;
    int bi = 0;
    while (rem >= NTILE - bi) { rem -= NTILE - bi; ++bi; }
    int bj = bi + rem;
    int rowBase = bi * TILE;
    int colBase = bj * TILE;

    int tid = threadIdx.x;
    int w = tid >> 6;             // wave 0..3 -> 2x2 of 64x64 subtiles
    int lane = tid & 63;
    int wm = w >> 1, wn = w & 1;
    int quad = lane >> 4;
    int l15 = lane & 15;

    f32x4 acc[4][4];
#pragma unroll
    for (int i = 0; i < 4; ++i)
#pragma unroll
        for (int j = 0; j < 4; ++j)
            acc[i][j] = (f32x4){0.f, 0.f, 0.f, 0.f};

    // staging: 1KB chunk = 16 rows x 64 B; lane l -> LDS (row l>>2, block
    // l&3); fetches global block (l&3)^swz(srow); chunk base (mult of 16
    // rows) doesn't perturb swz bits.
    int srow = lane >> 2;                       // 0..15 (row within chunk)
    int sbg = (lane & 3) ^ ((srow ^ (srow >> 2)) & 3);
    // wave w stages A-chunks {2w,2w+1} and B-chunks {2w,2w+1}
    const u8* gA = reps + (size_t)(rowBase + w * 32 + srow) * DK + sbg * 16;
    const u8* gB = reps + (size_t)(colBase + w * 32 + srow) * DK + sbg * 16;

    // fragment reads: row r = base + i*16 + l15; swz(r) = (l15^(l15>>2))&3
    // (i*16 and base are multiples of 16). One b128 per frag per kt.
    int rswz = (l15 ^ (l15 >> 2)) & 3;
    unsigned aOff[4], bOff[4];
#pragma unroll
    for (int i = 0; i < 4; ++i) {
        int ra = wm * 64 + i * 16 + l15;
        aOff[i] = ra * BKB + ((quad ^ rswz) << 4);
        int rb = wn * 64 + i * 16 + l15;
        bOff[i] = rb * BKB + ((quad ^ rswz) << 4);
    }

#define STAGE(buf, kt)                                                       \
    {                                                                        \
        _Pragma("unroll")                                                    \
        for (int c = 0; c < 2; ++c) {                                        \
            int chunk = 2 * w + c;                                           \
            __builtin_amdgcn_global_load_lds(                                \
                (const __attribute__((address_space(1))) void*)              \
                    (gA + (size_t)c * 16 * DK + (kt) * BKB),                 \
                (__attribute__((address_space(3))) void*)                    \
                    &A_s[buf][chunk * 1024], 16, 0, 0);                      \
            __builtin_amdgcn_global_load_lds(                                \
                (const __attribute__((address_space(1))) void*)              \
                    (gB + (size_t)c * 16 * DK + (kt) * BKB),                 \
                (__attribute__((address_space(3))) void*)                    \
                    &B_s[buf][chunk * 1024], 16, 0, 0);                      \
        }                                                                    \
    }
    // Per kt: quad q owns global k-chunk [16q,16q+16); lo/hi 8B -> 2 MFMAs.
#define COMPUTE(buf)                                                         \
    {                                                                        \
        v2l a2[4], b2[4];                                                    \
        _Pragma("unroll")                                                    \
        for (int i = 0; i < 4; ++i) {                                        \
            a2[i] = *(const v2l*)&A_s[buf][aOff[i]];                         \
            b2[i] = *(const v2l*)&B_s[buf][bOff[i]];                         \
        }                                                                    \
        _Pragma("unroll")                                                    \
        for (int i = 0; i < 4; ++i)                                          \
            _Pragma("unroll")                                                \
            for (int j = 0; j < 4; ++j) {                                    \
                acc[i][j] = __builtin_amdgcn_mfma_f32_16x16x32_fp8_fp8(      \
                    a2[i][0], b2[j][0], acc[i][j], 0, 0, 0);                 \
                acc[i][j] = __builtin_amdgcn_mfma_f32_16x16x32_fp8_fp8(      \
                    a2[i][1], b2[j][1], acc[i][j], 0, 0, 0);                 \
            }                                                                \
    }

    STAGE(0, 0)
    for (int kt = 0; kt < 14; kt += 2) {
        __syncthreads();          // drains buf0 loads (issued 1 phase ago)
        STAGE(1, kt + 1)
        COMPUTE(0)
        __syncthreads();
        STAGE(0, kt + 2)
        COMPUTE(1)
    }
    __syncthreads();
    STAGE(1, 15)
    COMPUTE(0)
    __syncthreads();
    COMPUTE(1)
#undef STAGE
#undef COMPUTE

    // Epilogue. C/D layout (m89-verified): col = lane&15, row = quad*4+reg.
    bool offd = (bi != bj);
    int lc[4], gcol[4];
#pragma unroll
    for (int j = 0; j < 4; ++j) {
        gcol[j] = colBase + wn * 64 + j * 16 + l15;
        lc[j] = labels[gcol[j] & (BHALF - 1)];   // 16KB table, cache-hot
    }
    float vD[16], vN[16];
    float colD[4] = {0.f, 0.f, 0.f, 0.f};
    float colN[4] = {0.f, 0.f, 0.f, 0.f};
#pragma unroll
    for (int i = 0; i < 4; ++i) {
#pragma unroll
        for (int reg = 0; reg < 4; ++reg) {
            int grow = rowBase + wm * 64 + i * 16 + quad * 4 + reg;
            int labr = labels[grow & (BHALF - 1)];
            float rD = 0.f, rN = 0.f;
#pragma unroll
            for (int j = 0; j < 4; ++j) {
                float e = exp2f(acc[i][j][reg] * EXP_SCALE);
                if (grow == gcol[j]) e = 0.f;   // diag (only when bi==bj)
                bool m = (lc[j] == labr);
                rD += e; if (m) rN += e;
                colD[j] += e; if (m) colN[j] += e;
            }
            vD[i * 4 + reg] = rD;
            vN[i * 4 + reg] = rN;
        }
    }
    // Packed butterfly over the 16 col-lanes: step m folds index bit of m;
    // afterwards lane l15 holds the full sum for row k = l15.
#pragma unroll
    for (int step = 0; step < 4; ++step) {
        const int m = 8 >> step;          // 8,4,2,1 (compile-time)
        const int h = 8 >> step;          // half-count = 8,4,2,1
        bool up = (l15 & m) != 0;
#pragma unroll
        for (int k = 0; k < h; ++k) {
            float sD = up ? vD[k] : vD[k + h];
            float sN = up ? vN[k] : vN[k + h];
            float kD = up ? vD[k + h] : vD[k];
            float kN = up ? vN[k + h] : vN[k];
            vD[k] = kD + __shfl_xor(sD, m, 64);
            vN[k] = kN + __shfl_xor(sN, m, 64);
        }
    }
    {
        int grow = rowBase + wm * 64 + (l15 >> 2) * 16 + quad * 4 + (l15 & 3);
        atomicAdd(&den[grow], vD[0]);
        atomicAdd(&nom[grow], vN[0]);
    }
    if (offd) {
        // packed butterfly over quads: afterwards quad q holds col j = q
        {
            bool up = (lane & 32) != 0;
#pragma unroll
            for (int k = 0; k < 2; ++k) {
                float sD = up ? colD[k] : colD[k + 2];
                float sN = up ? colN[k] : colN[k + 2];
                float kD = up ? colD[k + 2] : colD[k];
                float kN = up ? colN[k + 2] : colN[k];
                colD[k] = kD + __shfl_xor(sD, 32, 64);
                colN[k] = kN + __shfl_xor(sN, 32, 64);
            }
            bool up1 = (lane & 16) != 0;
            float sD = up1 ? colD[0] : colD[1];
            float sN = up1 ? colN[0] : colN[1];
            float kD = up1 ? colD[1] : colD[0];
            float kN = up1 ? colN[1] : colN[0];
            colD[0] = kD + __shfl_xor(sD, 16, 64);
            colN[0] = kN + __shfl_xor(sN, 16, 64);
        }
        int gc = colBase + wn * 64 + quad * 16 + l15;
        atomicAdd(&den[gc], colD[0]);
        atomicAdd(&nom[gc], colN[0]);
    }
}

__global__ __launch_bounds__(256) void finalize_kernel(
    const float* __restrict__ nom, const float* __restrict__ den,
    float* __restrict__ out) {
    int idx = blockIdx.x * 256 + threadIdx.x;   // 32 blocks x 256
    int t = threadIdx.x;
    float s = 0.f;
    if (idx < N2) s = logf(den[idx]) - logf(nom[idx]);   // -log(nom/den)
#pragma unroll
    for (int m = 1; m <= 32; m <<= 1) s += __shfl_xor(s, m, 64);
    __shared__ float red[4];
    if ((t & 63) == 0) red[t >> 6] = s;
    __syncthreads();
    if (t == 0)
        atomicAdd(out, (red[0] + red[1] + red[2] + red[3]) / (float)N2);
}

extern "C" void kernel_launch(void* const* d_in, const int* in_sizes, int n_in,
                              void* d_out, int out_size, void* d_ws, size_t ws_size,
                              hipStream_t stream) {
    const float* emb_i = (const float*)d_in[0];
    const float* emb_j = (const float*)d_in[1];
    const int* labels  = (const int*)d_in[2];
    float* out = (float*)d_out;

    char* ws = (char*)d_ws;
    u8* reps   = (u8*)ws;                                   // 8192*1024 = 8 MB
    float* nom = (float*)(ws + (size_t)N2 * DK);            // 32 KB
    float* den = nom + N2;                                  // 32 KB

    normalize_kernel<<<N2, 256, 0, stream>>>(emb_i, emb_j, reps, nom, out);
    gemm_loss_kernel<<<NBLK, 256, 0, stream>>>(reps, labels, nom, den);
    finalize_kernel<<<(N2 + 255) / 256, 256, 0, stream>>>(nom, den, out);
}

// Round 11
// 145.796 us; speedup vs baseline: 1.2802x; 1.2802x over previous
//
#include <hip/hip_runtime.h>
#include <hip/hip_bf16.h>
#include <hip/hip_fp8.h>

// TextualContrastiveLoss: B=4096, D=1024, NUM_CLASSES=100, T=0.5
//   z = l2norm(emb); reps = [z_i; z_j] (8192x1024)
//   sim = reps @ reps^T; e = exp(sim/T) with diag excluded
//   loss = mean_n( log(sum_m e) - log(sum_{m: lab match} e) )
//
// R3: 128x128 + upper-tri symmetry: 171us. R6 dbuf bf16: 158.
// R7: fp8 BKB=128: 136. R9: BKB=64, 32KB LDS, 4 blocks/CU: 103us.
// R10: 5 blocks/CU REGRESSED (unified reg budget 102 < 64 AGPR acc +
//      VGPRs -> scratch spills, WRITE 20->159MB). Conflict counter is
//      intrinsic b128 overhead (4/instr in R9+R10, 2x b64 count in R7).
// R11: revert to (256,4); MX-scaled mfma_scale_f32_32x32x64_f8f6f4
//      (K=64 = one staging buffer): 32 MFMA/kt -> 4 at 2x rate, unit
//      scales (E8M0 0x7F=1.0). Frags 32B/lane from two b128 reads
//      honoring the xor swizzle; 32x32 C/D epilogue (m74/m101 layout)
//      with 32-value packed butterfly.

#define BHALF 4096
#define N2 8192
#define DK 1024               // elements per row; fp8 => 1024 B
#define TILE 128
#define BKB 64                // K bytes staged per kt (16 kt total)
#define NTILE 64              // 8192/128
#define NBLK 2080             // 64*65/2 upper-tri tiles

typedef __attribute__((ext_vector_type(16))) float f32x16;
typedef __attribute__((ext_vector_type(4))) int v4i;
typedef __attribute__((ext_vector_type(8))) int v8i;
typedef unsigned char u8;

// exp(s/0.5) = exp2(s * 2*log2(e))
#define EXP_SCALE 2.8853900817779268f
#define UNIT_SCALE 0x7f7f7f7f    // E8M0 127 = 2^0 in every byte

__global__ __launch_bounds__(256) void normalize_kernel(
    const float* __restrict__ emb_i, const float* __restrict__ emb_j,
    u8* __restrict__ reps, float* __restrict__ nomden,
    float* __restrict__ out) {
    int r = blockIdx.x;           // 0..8191
    int t = threadIdx.x;          // 0..255, one float4 each
    int idx = r * 256 + t;
    if (idx < 2 * N2) nomden[idx] = 0.0f;     // fused zero of nom+den
    if (idx == 0) out[0] = 0.0f;
    const float* src = (r < BHALF) ? (emb_i + (size_t)r * DK)
                                   : (emb_j + (size_t)(r - BHALF) * DK);
    float4 v = ((const float4*)src)[t];
    float s = v.x * v.x + v.y * v.y + v.z * v.z + v.w * v.w;
#pragma unroll
    for (int m = 1; m <= 32; m <<= 1) s += __shfl_xor(s, m, 64);
    __shared__ float red[4];
    if ((t & 63) == 0) red[t >> 6] = s;
    __syncthreads();
    float tot = red[0] + red[1] + red[2] + red[3];
    float scale = 1.0f / fmaxf(sqrtf(tot), 1e-12f);
    __hip_fp8_e4m3 q0(v.x * scale), q1(v.y * scale),
                   q2(v.z * scale), q3(v.w * scale);
    uchar4 o = make_uchar4(q0.__x, q1.__x, q2.__x, q3.__x);
    ((uchar4*)(reps + (size_t)r * DK))[t] = o;
}

__global__ __launch_bounds__(256, 4) void gemm_loss_kernel(
    const u8* __restrict__ reps, const int* __restrict__ labels,
    float* __restrict__ nom, float* __restrict__ den) {
    // Double-buffered fp8 tiles: 2 x (A 8KB + B 8KB) = 32 KB.
    // Rows are 64 B = 4 x 16B blocks. Swizzle: LDS slot (row, b) holds
    // global block b ^ swz(row), swz(r) = (r ^ (r>>2)) & 3.
    __shared__ __align__(16) u8 A_s[2][TILE * BKB];
    __shared__ __align__(16) u8 B_s[2][TILE * BKB];

    // upper-triangle decode: row-major over bi<=bj
    int rem = blockIdx.x;
    int bi = 0;
    while (rem >= NTILE - bi) { rem -= NTILE - bi; ++bi; }
    int bj = bi + rem;
    int rowBase = bi * TILE;
    int colBase = bj * TILE;

    int tid = threadIdx.x;
    int w = tid >> 6;             // wave 0..3 -> 2x2 of 64x64 subtiles
    int lane = tid & 63;
    int wm = w >> 1, wn = w & 1;
    int hk = lane >> 5;           // lane half: k-chunk / C-row group
    int l31 = lane & 31;

    f32x16 acc[2][2];
#pragma unroll
    for (int i = 0; i < 2; ++i)
#pragma unroll
        for (int j = 0; j < 2; ++j)
#pragma unroll
            for (int r = 0; r < 16; ++r) acc[i][j][r] = 0.0f;

    // staging (unchanged from R9): 1KB chunk = 16 rows x 64 B; lane l ->
    // LDS (row l>>2, block l&3); fetches global block (l&3)^swz(srow)
    int srow = lane >> 2;
    int sbg = (lane & 3) ^ ((srow ^ (srow >> 2)) & 3);
    const u8* gA = reps + (size_t)(rowBase + w * 32 + srow) * DK + sbg * 16;
    const u8* gB = reps + (size_t)(colBase + w * 32 + srow) * DK + sbg * 16;

    // fragment reads: A frag i covers rows wm*64+i*32+l31, k-chunk
    // [32*hk, +32) = global blocks {2hk, 2hk+1} at LDS blocks g^swz(row);
    // swz(row) = (l31 ^ (l31>>2)) & 3 (tile bases are multiples of 32).
    int rswz = (l31 ^ (l31 >> 2)) & 3;
    unsigned aLo[2], aHi[2], bLo[2], bHi[2];
#pragma unroll
    for (int i = 0; i < 2; ++i) {
        int ra = (wm * 64 + i * 32 + l31) * BKB;
        aLo[i] = ra + (((2 * hk) ^ rswz) << 4);
        aHi[i] = ra + (((2 * hk + 1) ^ rswz) << 4);
        int rb = (wn * 64 + i * 32 + l31) * BKB;
        bLo[i] = rb + (((2 * hk) ^ rswz) << 4);
        bHi[i] = rb + (((2 * hk + 1) ^ rswz) << 4);
    }

#define STAGE(buf, kt)                                                       \
    {                                                                        \
        _Pragma("unroll")                                                    \
        for (int c = 0; c < 2; ++c) {                                        \
            int chunk = 2 * w + c;                                           \
            __builtin_amdgcn_global_load_lds(                                \
                (const __attribute__((address_space(1))) void*)              \
                    (gA + (size_t)c * 16 * DK + (kt) * BKB),                 \
                (__attribute__((address_space(3))) void*)                    \
                    &A_s[buf][chunk * 1024], 16, 0, 0);                      \
            __builtin_amdgcn_global_load_lds(                                \
                (const __attribute__((address_space(1))) void*)              \
                    (gB + (size_t)c * 16 * DK + (kt) * BKB),                 \
                (__attribute__((address_space(3))) void*)                    \
                    &B_s[buf][chunk * 1024], 16, 0, 0);                      \
        }                                                                    \
    }
    // Per kt: 4 MX MFMAs (K=64) consuming the whole staged buffer.
#define COMPUTE(buf)                                                         \
    {                                                                        \
        v8i aF[2], bF[2];                                                    \
        _Pragma("unroll")                                                    \
        for (int i = 0; i < 2; ++i) {                                        \
            v4i alo = *(const v4i*)&A_s[buf][aLo[i]];                        \
            v4i ahi = *(const v4i*)&A_s[buf][aHi[i]];                        \
            aF[i] = __builtin_shufflevector(alo, ahi, 0,1,2,3,4,5,6,7);      \
            v4i blo = *(const v4i*)&B_s[buf][bLo[i]];                        \
            v4i bhi = *(const v4i*)&B_s[buf][bHi[i]];                        \
            bF[i] = __builtin_shufflevector(blo, bhi, 0,1,2,3,4,5,6,7);      \
        }                                                                    \
        _Pragma("unroll")                                                    \
        for (int i = 0; i < 2; ++i)                                          \
            _Pragma("unroll")                                                \
            for (int j = 0; j < 2; ++j)                                      \
                acc[i][j] = __builtin_amdgcn_mfma_scale_f32_32x32x64_f8f6f4( \
                    aF[i], bF[j], acc[i][j], 0, 0,                           \
                    0, UNIT_SCALE, 0, UNIT_SCALE);                           \
    }

    STAGE(0, 0)
    for (int kt = 0; kt < 14; kt += 2) {
        __syncthreads();          // drains buf0 loads (issued 1 phase ago)
        STAGE(1, kt + 1)
        COMPUTE(0)
        __syncthreads();
        STAGE(0, kt + 2)
        COMPUTE(1)
    }
    __syncthreads();
    STAGE(1, 15)
    COMPUTE(0)
    __syncthreads();
    COMPUTE(1)
#undef STAGE
#undef COMPUTE

    // Epilogue. 32x32 C/D layout (m74/m101-verified, dtype-independent):
    //   col = lane&31, row = (reg&3) + 8*(reg>>2) + 4*(lane>>5)
    bool offd = (bi != bj);
    int lc[2], gcol[2];
#pragma unroll
    for (int j = 0; j < 2; ++j) {
        gcol[j] = colBase + wn * 64 + j * 32 + l31;
        lc[j] = labels[gcol[j] & (BHALF - 1)];   // 16KB table, cache-hot
    }
    float vD[32], vN[32];
    float colD[2] = {0.f, 0.f}, colN[2] = {0.f, 0.f};
#pragma unroll
    for (int i = 0; i < 2; ++i) {
#pragma unroll
        for (int reg = 0; reg < 16; ++reg) {
            int rowIn = (reg & 3) + 8 * (reg >> 2) + 4 * hk;
            int grow = rowBase + wm * 64 + i * 32 + rowIn;
            int labr = labels[grow & (BHALF - 1)];
            float rD = 0.f, rN = 0.f;
#pragma unroll
            for (int j = 0; j < 2; ++j) {
                float e = exp2f(acc[i][j][reg] * EXP_SCALE);
                if (grow == gcol[j]) e = 0.f;   // diag (only when bi==bj)
                bool m = (lc[j] == labr);
                rD += e; if (m) rN += e;
                colD[j] += e; if (m) colN[j] += e;
            }
            vD[i * 16 + reg] = rD;
            vN[i * 16 + reg] = rN;
        }
    }
    // Packed butterfly: 32 row-partials over the 32 col-lanes of this
    // half; afterwards lane l31 holds the sum for k = l31 (i=k>>4,
    // reg=k&15). Halves hk=0/1 own disjoint row sets (rowIn +4*hk).
#pragma unroll
    for (int step = 0; step < 5; ++step) {
        const int m = 16 >> step;         // 16,8,4,2,1
        const int h = 16 >> step;
        bool up = (l31 & m) != 0;
#pragma unroll
        for (int k = 0; k < h; ++k) {
            float sD = up ? vD[k] : vD[k + h];
            float sN = up ? vN[k] : vN[k + h];
            float kD = up ? vD[k + h] : vD[k];
            float kN = up ? vN[k + h] : vN[k];
            vD[k] = kD + __shfl_xor(sD, m, 64);
            vN[k] = kN + __shfl_xor(sN, m, 64);
        }
    }
    {
        int grow = rowBase + wm * 64 + (l31 >> 4) * 32 +
                   ((l31 & 3) + 8 * ((l31 >> 2) & 3) + 4 * hk);
        atomicAdd(&den[grow], vD[0]);
        atomicAdd(&nom[grow], vN[0]);
    }
    if (offd) {
        // col sums: fold across the two lane-halves (row groups), then
        // half 0 scatters cols l31 of each j-tile.
#pragma unroll
        for (int j = 0; j < 2; ++j) {
            float cd = colD[j] + __shfl_xor(colD[j], 32, 64);
            float cn = colN[j] + __shfl_xor(colN[j], 32, 64);
            if (hk == 0) {
                atomicAdd(&den[gcol[j]], cd);
                atomicAdd(&nom[gcol[j]], cn);
            }
        }
    }
}

__global__ __launch_bounds__(256) void finalize_kernel(
    const float* __restrict__ nom, const float* __restrict__ den,
    float* __restrict__ out) {
    int idx = blockIdx.x * 256 + threadIdx.x;   // 32 blocks x 256
    int t = threadIdx.x;
    float s = 0.f;
    if (idx < N2) s = logf(den[idx]) - logf(nom[idx]);   // -log(nom/den)
#pragma unroll
    for (int m = 1; m <= 32; m <<= 1) s += __shfl_xor(s, m, 64);
    __shared__ float red[4];
    if ((t & 63) == 0) red[t >> 6] = s;
    __syncthreads();
    if (t == 0)
        atomicAdd(out, (red[0] + red[1] + red[2] + red[3]) / (float)N2);
}

extern "C" void kernel_launch(void* const* d_in, const int* in_sizes, int n_in,
                              void* d_out, int out_size, void* d_ws, size_t ws_size,
                              hipStream_t stream) {
    const float* emb_i = (const float*)d_in[0];
    const float* emb_j = (const float*)d_in[1];
    const int* labels  = (const int*)d_in[2];
    float* out = (float*)d_out;

    char* ws = (char*)d_ws;
    u8* reps   = (u8*)ws;                                   // 8192*1024 = 8 MB
    float* nom = (float*)(ws + (size_t)N2 * DK);            // 32 KB
    float* den = nom + N2;                                  // 32 KB

    normalize_kernel<<<N2, 256, 0, stream>>>(emb_i, emb_j, reps, nom, out);
    gemm_loss_kernel<<<NBLK, 256, 0, stream>>>(reps, labels, nom, den);
    finalize_kernel<<<(N2 + 255) / 256, 256, 0, stream>>>(nom, den, out);
}

// Round 12
// 138.691 us; speedup vs baseline: 1.3458x; 1.0512x over previous
//
#include <hip/hip_runtime.h>
#include <hip/hip_bf16.h>
#include <hip/hip_fp8.h>

// TextualContrastiveLoss: B=4096, D=1024, NUM_CLASSES=100, T=0.5
//   z = l2norm(emb); reps = [z_i; z_j] (8192x1024)
//   sim = reps @ reps^T; e = exp(sim/T) with diag excluded
//   loss = mean_n( log(sum_m e) - log(sum_{m: lab match} e) )
//
// R3: 128x128 + upper-tri symmetry: 171us. R7: fp8: 136.
// R9: BKB=64, 32KB LDS, 4 blocks/CU: 103us. R10: 5 blocks/CU spilled.
// R11: MX mfma_scale_32x32x64 (4 MFMA/kt, unit scales): 71us. All pipes
//      <=31% -> last structural stall is __syncthreads' implicit
//      vmcnt(0) drain (exposes HBM-miss latency of loads issued only
//      ~350cyc earlier, every kt).
// R12: hand-rolled sync (AITER pattern, s02): s_waitcnt vmcnt(16) +
//      raw s_barrier -> waits only for loads issued TWO phases (~700cyc)
//      back; the newer 16 prefetch loads stay in flight across the
//      barrier. vmcnt never hits 0 until the last kt. R8 already
//      HW-validated manual WAITVM correctness on this kernel family.

#define BHALF 4096
#define N2 8192
#define DK 1024               // elements per row; fp8 => 1024 B
#define TILE 128
#define BKB 64                // K bytes staged per kt (16 kt total)
#define NTILE 64              // 8192/128
#define NBLK 2080             // 64*65/2 upper-tri tiles

typedef __attribute__((ext_vector_type(16))) float f32x16;
typedef __attribute__((ext_vector_type(4))) int v4i;
typedef __attribute__((ext_vector_type(8))) int v8i;
typedef unsigned char u8;

// exp(s/0.5) = exp2(s * 2*log2(e))
#define EXP_SCALE 2.8853900817779268f
#define UNIT_SCALE 0x7f7f7f7f    // E8M0 127 = 2^0 in every byte

// raw barrier / waitcnt — no compiler-inserted vmcnt(0) drain
#define WAITVM(n) asm volatile("s_waitcnt vmcnt(" #n ")" ::: "memory")
#define BAR()     asm volatile("s_barrier" ::: "memory")

__global__ __launch_bounds__(256) void normalize_kernel(
    const float* __restrict__ emb_i, const float* __restrict__ emb_j,
    u8* __restrict__ reps, float* __restrict__ nomden,
    float* __restrict__ out) {
    int r = blockIdx.x;           // 0..8191
    int t = threadIdx.x;          // 0..255, one float4 each
    int idx = r * 256 + t;
    if (idx < 2 * N2) nomden[idx] = 0.0f;     // fused zero of nom+den
    if (idx == 0) out[0] = 0.0f;
    const float* src = (r < BHALF) ? (emb_i + (size_t)r * DK)
                                   : (emb_j + (size_t)(r - BHALF) * DK);
    float4 v = ((const float4*)src)[t];
    float s = v.x * v.x + v.y * v.y + v.z * v.z + v.w * v.w;
#pragma unroll
    for (int m = 1; m <= 32; m <<= 1) s += __shfl_xor(s, m, 64);
    __shared__ float red[4];
    if ((t & 63) == 0) red[t >> 6] = s;
    __syncthreads();
    float tot = red[0] + red[1] + red[2] + red[3];
    float scale = 1.0f / fmaxf(sqrtf(tot), 1e-12f);
    __hip_fp8_e4m3 q0(v.x * scale), q1(v.y * scale),
                   q2(v.z * scale), q3(v.w * scale);
    uchar4 o = make_uchar4(q0.__x, q1.__x, q2.__x, q3.__x);
    ((uchar4*)(reps + (size_t)r * DK))[t] = o;
}

__global__ __launch_bounds__(256, 4) void gemm_loss_kernel(
    const u8* __restrict__ reps, const int* __restrict__ labels,
    float* __restrict__ nom, float* __restrict__ den) {
    // Double-buffered fp8 tiles: 2 x (A 8KB + B 8KB) = 32 KB.
    // Rows are 64 B = 4 x 16B blocks. Swizzle: LDS slot (row, b) holds
    // global block b ^ swz(row), swz(r) = (r ^ (r>>2)) & 3.
    __shared__ __align__(16) u8 A_s[2][TILE * BKB];
    __shared__ __align__(16) u8 B_s[2][TILE * BKB];

    // upper-triangle decode: row-major over bi<=bj
    int rem = blockIdx.x;
    int bi = 0;
    while (rem >= NTILE - bi) { rem -= NTILE - bi; ++bi; }
    int bj = bi + rem;
    int rowBase = bi * TILE;
    int colBase = bj * TILE;

    int tid = threadIdx.x;
    int w = tid >> 6;             // wave 0..3 -> 2x2 of 64x64 subtiles
    int lane = tid & 63;
    int wm = w >> 1, wn = w & 1;
    int hk = lane >> 5;           // lane half: k-chunk / C-row group
    int l31 = lane & 31;

    f32x16 acc[2][2];
#pragma unroll
    for (int i = 0; i < 2; ++i)
#pragma unroll
        for (int j = 0; j < 2; ++j)
#pragma unroll
            for (int r = 0; r < 16; ++r) acc[i][j][r] = 0.0f;

    // staging: 1KB chunk = 16 rows x 64 B; lane l -> LDS (row l>>2,
    // block l&3); fetches global block (l&3)^swz(srow)
    int srow = lane >> 2;
    int sbg = (lane & 3) ^ ((srow ^ (srow >> 2)) & 3);
    const u8* gA = reps + (size_t)(rowBase + w * 32 + srow) * DK + sbg * 16;
    const u8* gB = reps + (size_t)(colBase + w * 32 + srow) * DK + sbg * 16;

    // fragment reads: A frag i covers rows wm*64+i*32+l31, k-chunk
    // [32*hk, +32) = global blocks {2hk, 2hk+1} at LDS blocks g^swz(row)
    int rswz = (l31 ^ (l31 >> 2)) & 3;
    unsigned aLo[2], aHi[2], bLo[2], bHi[2];
#pragma unroll
    for (int i = 0; i < 2; ++i) {
        int ra = (wm * 64 + i * 32 + l31) * BKB;
        aLo[i] = ra + (((2 * hk) ^ rswz) << 4);
        aHi[i] = ra + (((2 * hk + 1) ^ rswz) << 4);
        int rb = (wn * 64 + i * 32 + l31) * BKB;
        bLo[i] = rb + (((2 * hk) ^ rswz) << 4);
        bHi[i] = rb + (((2 * hk + 1) ^ rswz) << 4);
    }

#define STAGE(buf, kt)                                                       \
    {                                                                        \
        _Pragma("unroll")                                                    \
        for (int c = 0; c < 2; ++c) {                                        \
            int chunk = 2 * w + c;                                           \
            __builtin_amdgcn_global_load_lds(                                \
                (const __attribute__((address_space(1))) void*)              \
                    (gA + (size_t)c * 16 * DK + (kt) * BKB),                 \
                (__attribute__((address_space(3))) void*)                    \
                    &A_s[buf][chunk * 1024], 16, 0, 0);                      \
            __builtin_amdgcn_global_load_lds(                                \
                (const __attribute__((address_space(1))) void*)              \
                    (gB + (size_t)c * 16 * DK + (kt) * BKB),                 \
                (__attribute__((address_space(3))) void*)                    \
                    &B_s[buf][chunk * 1024], 16, 0, 0);                      \
        }                                                                    \
    }
    // Per kt: 4 MX MFMAs (K=64) consuming the whole staged buffer.
#define COMPUTE(buf)                                                         \
    {                                                                        \
        v8i aF[2], bF[2];                                                    \
        _Pragma("unroll")                                                    \
        for (int i = 0; i < 2; ++i) {                                        \
            v4i alo = *(const v4i*)&A_s[buf][aLo[i]];                        \
            v4i ahi = *(const v4i*)&A_s[buf][aHi[i]];                        \
            aF[i] = __builtin_shufflevector(alo, ahi, 0,1,2,3,4,5,6,7);      \
            v4i blo = *(const v4i*)&B_s[buf][bLo[i]];                        \
            v4i bhi = *(const v4i*)&B_s[buf][bHi[i]];                        \
            bF[i] = __builtin_shufflevector(blo, bhi, 0,1,2,3,4,5,6,7);      \
        }                                                                    \
        _Pragma("unroll")                                                    \
        for (int i = 0; i < 2; ++i)                                          \
            _Pragma("unroll")                                                \
            for (int j = 0; j < 2; ++j)                                      \
                acc[i][j] = __builtin_amdgcn_mfma_scale_f32_32x32x64_f8f6f4( \
                    aF[i], bF[j], acc[i][j], 0, 0,                           \
                    0, UNIT_SCALE, 0, UNIT_SCALE);                           \
    }

    // Pipeline: 32 loads in flight; vmcnt(16) waits only for the buffer
    // staged TWO phases ago; bare s_barrier after compute (no drain)
    // protects the overwrite. vmcnt hits 0 only at the final kt.
    STAGE(0, 0)
    STAGE(1, 1)
    for (int kt = 0; kt < 12; kt += 2) {
        WAITVM(16); BAR();        // buf0 (staged 2 phases ago) ready
        COMPUTE(0)
        BAR();                    // all waves done reading buf0
        STAGE(0, kt + 2)
        WAITVM(16); BAR();        // buf1 ready
        COMPUTE(1)
        BAR();
        STAGE(1, kt + 3)
    }
    WAITVM(16); BAR();
    COMPUTE(0)                    // kt 12
    BAR();
    STAGE(0, 14)
    WAITVM(16); BAR();
    COMPUTE(1)                    // kt 13
    BAR();
    STAGE(1, 15)
    WAITVM(16); BAR();
    COMPUTE(0)                    // kt 14
    WAITVM(0); BAR();
    COMPUTE(1)                    // kt 15
#undef STAGE
#undef COMPUTE

    // Epilogue. 32x32 C/D layout (m74/m101-verified, dtype-independent):
    //   col = lane&31, row = (reg&3) + 8*(reg>>2) + 4*(lane>>5)
    bool offd = (bi != bj);
    int lc[2], gcol[2];
#pragma unroll
    for (int j = 0; j < 2; ++j) {
        gcol[j] = colBase + wn * 64 + j * 32 + l31;
        lc[j] = labels[gcol[j] & (BHALF - 1)];   // 16KB table, cache-hot
    }
    float vD[32], vN[32];
    float colD[2] = {0.f, 0.f}, colN[2] = {0.f, 0.f};
#pragma unroll
    for (int i = 0; i < 2; ++i) {
#pragma unroll
        for (int reg = 0; reg < 16; ++reg) {
            int rowIn = (reg & 3) + 8 * (reg >> 2) + 4 * hk;
            int grow = rowBase + wm * 64 + i * 32 + rowIn;
            int labr = labels[grow & (BHALF - 1)];
            float rD = 0.f, rN = 0.f;
#pragma unroll
            for (int j = 0; j < 2; ++j) {
                float e = exp2f(acc[i][j][reg] * EXP_SCALE);
                if (grow == gcol[j]) e = 0.f;   // diag (only when bi==bj)
                bool m = (lc[j] == labr);
                rD += e; if (m) rN += e;
                colD[j] += e; if (m) colN[j] += e;
            }
            vD[i * 16 + reg] = rD;
            vN[i * 16 + reg] = rN;
        }
    }
    // Packed butterfly: 32 row-partials over the 32 col-lanes of this
    // half; afterwards lane l31 holds the sum for k = l31.
#pragma unroll
    for (int step = 0; step < 5; ++step) {
        const int m = 16 >> step;         // 16,8,4,2,1
        const int h = 16 >> step;
        bool up = (l31 & m) != 0;
#pragma unroll
        for (int k = 0; k < h; ++k) {
            float sD = up ? vD[k] : vD[k + h];
            float sN = up ? vN[k] : vN[k + h];
            float kD = up ? vD[k + h] : vD[k];
            float kN = up ? vN[k + h] : vN[k];
            vD[k] = kD + __shfl_xor(sD, m, 64);
            vN[k] = kN + __shfl_xor(sN, m, 64);
        }
    }
    {
        int grow = rowBase + wm * 64 + (l31 >> 4) * 32 +
                   ((l31 & 3) + 8 * ((l31 >> 2) & 3) + 4 * hk);
        atomicAdd(&den[grow], vD[0]);
        atomicAdd(&nom[grow], vN[0]);
    }
    if (offd) {
        // col sums: fold across the two lane-halves, half 0 scatters
#pragma unroll
        for (int j = 0; j < 2; ++j) {
            float cd = colD[j] + __shfl_xor(colD[j], 32, 64);
            float cn = colN[j] + __shfl_xor(colN[j], 32, 64);
            if (hk == 0) {
                atomicAdd(&den[gcol[j]], cd);
                atomicAdd(&nom[gcol[j]], cn);
            }
        }
    }
}

__global__ __launch_bounds__(256) void finalize_kernel(
    const float* __restrict__ nom, const float* __restrict__ den,
    float* __restrict__ out) {
    int idx = blockIdx.x * 256 + threadIdx.x;   // 32 blocks x 256
    int t = threadIdx.x;
    float s = 0.f;
    if (idx < N2) s = logf(den[idx]) - logf(nom[idx]);   // -log(nom/den)
#pragma unroll
    for (int m = 1; m <= 32; m <<= 1) s += __shfl_xor(s, m, 64);
    __shared__ float red[4];
    if ((t & 63) == 0) red[t >> 6] = s;
    __syncthreads();
    if (t == 0)
        atomicAdd(out, (red[0] + red[1] + red[2] + red[3]) / (float)N2);
}

extern "C" void kernel_launch(void* const* d_in, const int* in_sizes, int n_in,
                              void* d_out, int out_size, void* d_ws, size_t ws_size,
                              hipStream_t stream) {
    const float* emb_i = (const float*)d_in[0];
    const float* emb_j = (const float*)d_in[1];
    const int* labels  = (const int*)d_in[2];
    float* out = (float*)d_out;

    char* ws = (char*)d_ws;
    u8* reps   = (u8*)ws;                                   // 8192*1024 = 8 MB
    float* nom = (float*)(ws + (size_t)N2 * DK);            // 32 KB
    float* den = nom + N2;                                  // 32 KB

    normalize_kernel<<<N2, 256, 0, stream>>>(emb_i, emb_j, reps, nom, out);
    gemm_loss_kernel<<<NBLK, 256, 0, stream>>>(reps, labels, nom, den);
    finalize_kernel<<<(N2 + 255) / 256, 256, 0, stream>>>(nom, den, out);
}